// Round 10
// baseline (99.722 us; speedup 1.0000x reference)
//
#include <hip/hip_runtime.h>
#include <hip/hip_bf16.h>
#include <hip/hip_fp8.h>

#define N_NODES 10000
#define N_EDGES 160000
#define D_IN 512
#define D_OUT 512
#define K_TOT 1024   // concat [x | neigh]
#define BK 64

typedef __attribute__((ext_vector_type(8))) short short8;
typedef __attribute__((ext_vector_type(4))) float f32x4;

__device__ __forceinline__ void load_lds16(const void* g, void* l) {
    __builtin_amdgcn_global_load_lds(
        (const __attribute__((address_space(1))) void*)g,
        (__attribute__((address_space(3))) void*)l, 16, 0, 0);
}

// ---------------- K1: count (blocks 0..624) + W transpose (blocks 625..1136) ----------------

__global__ __launch_bounds__(256) void k1_count_convw(const int* __restrict__ dst,
                                                      int* __restrict__ deg,
                                                      const float* __restrict__ Wself,
                                                      const float* __restrict__ Wneigh,
                                                      __hip_bfloat16* __restrict__ Wt) {
    int bid = blockIdx.x;
    if (bid < 625) {
        int e = bid * 256 + threadIdx.x;
        atomicAdd(&deg[dst[e]], 1);
        return;
    }
    __shared__ float tl[32][33];
    int b = bid - 625;
    int kt0 = (b & 31) * 32;
    int nt0 = (b >> 5) * 32;
    int tx = threadIdx.x & 31, ty = threadIdx.x >> 5;
    const float* Wsrc = (kt0 < D_IN) ? (Wself + (size_t)kt0 * D_OUT)
                                     : (Wneigh + (size_t)(kt0 - D_IN) * D_OUT);
#pragma unroll
    for (int p = 0; p < 4; ++p)
        tl[p * 8 + ty][tx] = Wsrc[(size_t)(p * 8 + ty) * D_OUT + nt0 + tx];
    __syncthreads();
#pragma unroll
    for (int p = 0; p < 4; ++p)
        Wt[(size_t)(nt0 + p * 8 + ty) * K_TOT + kt0 + tx] =
            __float2bfloat16(tl[tx][p * 8 + ty]);
}

// ---------------- K2: scan (block 0) + convert_x bf16+fp8 (blocks 1..625) ----------------

__global__ __launch_bounds__(1024) void k2_scan_convx(const int* __restrict__ deg,
                                                      int* __restrict__ offsets,
                                                      int* __restrict__ cursor,
                                                      const float* __restrict__ x,
                                                      __hip_bfloat16* __restrict__ A,
                                                      unsigned char* __restrict__ x8) {
    int bid = blockIdx.x;
    int tid = threadIdx.x;
    if (bid == 0) {
        __shared__ int wsum[16];
        int wave = tid >> 6, lane = tid & 63;
        int running = 0;
        for (int c = 0; c < 10; ++c) {
            int i = c * 1024 + tid;
            int v = (i < N_NODES) ? deg[i] : 0;
            int s = v;
#pragma unroll
            for (int off = 1; off < 64; off <<= 1) {
                int t = __shfl_up(s, off);
                if (lane >= off) s += t;
            }
            if (lane == 63) wsum[wave] = s;
            __syncthreads();
            if (wave == 0) {
                int w = (lane < 16) ? wsum[lane] : 0;
#pragma unroll
                for (int off = 1; off < 16; off <<= 1) {
                    int t = __shfl_up(w, off);
                    if (lane >= off) w += t;
                }
                if (lane < 16) wsum[lane] = w;
            }
            __syncthreads();
            int wprefix = (wave > 0) ? wsum[wave - 1] : 0;
            int excl = running + wprefix + s - v;
            if (i < N_NODES) { offsets[i] = excl; cursor[i] = excl; }
            running += wsum[15];
            __syncthreads();
        }
        if (tid == 0) offsets[N_NODES] = running;
    } else {
        int gid = (bid - 1) * 1024 + tid;          // 0 .. 639999
        int row = gid >> 6;
        int col = (gid & 63) * 8;
        const float4* p = (const float4*)(x + (size_t)row * D_IN + col);
        float4 u = p[0], v = p[1];
        float f[8] = {u.x, u.y, u.z, u.w, v.x, v.y, v.z, v.w};
        union { short8 s; __hip_bfloat16 h[8]; } o;
        unsigned long long q8 = 0;
#pragma unroll
        for (int j = 0; j < 8; ++j) {
            o.h[j] = __float2bfloat16(f[j]);
            __hip_fp8_e4m3 q(f[j]);
            q8 |= ((unsigned long long)q.__x) << (8 * j);
        }
        *(short8*)(A + (size_t)row * K_TOT + col) = o.s;
        *(unsigned long long*)(x8 + (size_t)row * D_IN + col) = q8;
    }
}

// ---------------- K3: scatter ----------------

__global__ __launch_bounds__(256) void scatter_kernel(const int* __restrict__ src,
                                                      const int* __restrict__ dst,
                                                      int* __restrict__ cursor,
                                                      int* __restrict__ csr_src) {
    int e = blockIdx.x * 256 + threadIdx.x;
    int p = atomicAdd(&cursor[dst[e]], 1);
    csr_src[p] = src[e];
}

// ---------------- K4: aggregation — one wave per node, fp8 gather (0.5KB rows) ----------------

__device__ __forceinline__ void add_fp8x8(float* acc, unsigned long long v) {
#pragma unroll
    for (int i = 0; i < 8; ++i) {
        __hip_fp8_e4m3 q;
        q.__x = (unsigned char)(v >> (8 * i));
        acc[i] += (float)q;
    }
}

__global__ __launch_bounds__(256) void aggregate_kernel(const int* __restrict__ offsets,
                                                        const int* __restrict__ csr_src,
                                                        const unsigned char* __restrict__ x8,
                                                        __hip_bfloat16* __restrict__ A) {
    int wave = threadIdx.x >> 6, lane = threadIdx.x & 63;
    int node = blockIdx.x * 4 + wave;
    if (node >= N_NODES) return;
    int e0 = offsets[node], e1 = offsets[node + 1];
    int cnt = e1 - e0;
    int d0 = lane * 8;                        // 8 fp8 per lane = 8B; 64 lanes = 512B row
    float acc[8];
#pragma unroll
    for (int i = 0; i < 8; ++i) acc[i] = 0.f;

    for (int base = 0; base < cnt; base += 64) {
        int m = cnt - base; if (m > 64) m = 64;
        int idx = (base + lane < cnt) ? csr_src[e0 + base + lane] : 0;
        int j = 0;
        for (; j + 3 < m; j += 4) {
            int s0 = __shfl(idx, j),     s1 = __shfl(idx, j + 1);
            int s2 = __shfl(idx, j + 2), s3 = __shfl(idx, j + 3);
            unsigned long long v0 = *(const unsigned long long*)(x8 + (size_t)s0 * D_IN + d0);
            unsigned long long v1 = *(const unsigned long long*)(x8 + (size_t)s1 * D_IN + d0);
            unsigned long long v2 = *(const unsigned long long*)(x8 + (size_t)s2 * D_IN + d0);
            unsigned long long v3 = *(const unsigned long long*)(x8 + (size_t)s3 * D_IN + d0);
            add_fp8x8(acc, v0); add_fp8x8(acc, v1);
            add_fp8x8(acc, v2); add_fp8x8(acc, v3);
        }
        for (; j < m; ++j) {
            int s0 = __shfl(idx, j);
            unsigned long long v0 = *(const unsigned long long*)(x8 + (size_t)s0 * D_IN + d0);
            add_fp8x8(acc, v0);
        }
    }
    float inv = 1.0f / fmaxf((float)cnt, 1.0f);
    union { short8 s; __hip_bfloat16 h[8]; } o;
#pragma unroll
    for (int i = 0; i < 8; ++i) o.h[i] = __float2bfloat16(acc[i] * inv);
    *(short8*)(A + (size_t)node * K_TOT + D_IN + d0) = o.s;
}

// ---------------- K5: GEMM 128x64 block, 2 waves x (64x64 wave-tile), BK=64,
//                  swizzled LDS + dbuf prefetch + XCD-clustered grid ----------------

__global__ __launch_bounds__(128) void gemm_kernel(const short* __restrict__ A,
                                                   const short* __restrict__ Wt,
                                                   const float* __restrict__ bias,
                                                   float* __restrict__ H) {
    __shared__ __align__(16) short smA[2][128 * BK];   // 2 x 16 KB
    __shared__ __align__(16) short smB[2][64 * BK];    // 2 x 8 KB
    const int tid = threadIdx.x;                       // 0..127
    const int wave = tid >> 6, lane = tid & 63;

    const int s = (blockIdx.x & 7) * 79 + (blockIdx.x >> 3);   // bijective, 632=8*79
    const int m0 = (s >> 3) * 128;
    const int n0 = (s & 7) * 64;

    const int rr = lane & 15, kq = lane >> 4;
    const int srow8 = lane >> 3;            // row within 8-row chunk
    const int sslot = (lane & 7) ^ srow8;   // pre-swizzled global 16B-chunk index

    f32x4 acc[4][4];
#pragma unroll
    for (int i = 0; i < 4; ++i)
#pragma unroll
        for (int j = 0; j < 4; ++j) acc[i][j] = (f32x4){0.f, 0.f, 0.f, 0.f};

    // A: 8 issues cover 128 rows; issue i, wave w -> rows 16i+8w+srow8
    int garow[8];
#pragma unroll
    for (int i = 0; i < 8; ++i) {
        int gr = m0 + i * 16 + wave * 8 + srow8;
        garow[i] = (gr > N_NODES - 1) ? N_NODES - 1 : gr;
    }
    // B: 4 issues cover 64 rows
    int gbrow[4];
#pragma unroll
    for (int i = 0; i < 4; ++i) gbrow[i] = n0 + i * 16 + wave * 8 + srow8;

    auto stage = [&](int buf, int kt) {
        const int kbase = kt * BK + sslot * 8;
#pragma unroll
        for (int i = 0; i < 8; ++i)
            load_lds16(A + (size_t)garow[i] * K_TOT + kbase,
                       (char*)smA[buf] + i * 2048 + wave * 1024);
#pragma unroll
        for (int i = 0; i < 4; ++i)
            load_lds16(Wt + (size_t)gbrow[i] * K_TOT + kbase,
                       (char*)smB[buf] + i * 2048 + wave * 1024);
    };

    stage(0, 0);
    __syncthreads();

    for (int kt = 0; kt < K_TOT / BK; ++kt) {
        const int cur = kt & 1;
        if (kt + 1 < K_TOT / BK) stage(cur ^ 1, kt + 1);

        short8 afr[2][4], bfr[2][4];
#pragma unroll
        for (int ks = 0; ks < 2; ++ks) {
#pragma unroll
            for (int mf = 0; mf < 4; ++mf) {
                int row = wave * 64 + mf * 16 + rr;
                int slot = (ks * 4 + kq) ^ (row & 7);
                afr[ks][mf] = *(const short8*)&smA[cur][row * 64 + slot * 8];
            }
#pragma unroll
            for (int nf = 0; nf < 4; ++nf) {
                int row = nf * 16 + rr;
                int slot = (ks * 4 + kq) ^ (row & 7);
                bfr[ks][nf] = *(const short8*)&smB[cur][row * 64 + slot * 8];
            }
        }
#pragma unroll
        for (int ks = 0; ks < 2; ++ks)
#pragma unroll
            for (int mf = 0; mf < 4; ++mf)
#pragma unroll
                for (int nf = 0; nf < 4; ++nf)
                    acc[mf][nf] = __builtin_amdgcn_mfma_f32_16x16x32_bf16(
                        afr[ks][mf], bfr[ks][nf], acc[mf][nf], 0, 0, 0);
        __syncthreads();
    }

    // epilogue: bias + leaky_relu.  C/D: col=lane&15, row=(lane>>4)*4+reg
#pragma unroll
    for (int mf = 0; mf < 4; ++mf) {
        int row = m0 + wave * 64 + mf * 16 + kq * 4;
#pragma unroll
        for (int nf = 0; nf < 4; ++nf) {
            int col = n0 + nf * 16 + rr;
            float bv = bias[col];
#pragma unroll
            for (int r = 0; r < 4; ++r) {
                int grow = row + r;
                if (grow < N_NODES) {
                    float v = acc[mf][nf][r] + bv;
                    v = (v >= 0.f) ? v : 0.01f * v;
                    H[(size_t)grow * D_OUT + col] = v;
                }
            }
        }
    }
}

// ---------------- K6: row-wise L2 normalize (in place) ----------------

__global__ __launch_bounds__(256) void normalize_kernel(float* __restrict__ H) {
    int wave = threadIdx.x >> 6, lane = threadIdx.x & 63;
    int row = blockIdx.x * 4 + wave;
    if (row >= N_NODES) return;
    float4* p = (float4*)(H + (size_t)row * D_OUT + lane * 8);
    float4 u = p[0], v = p[1];
    float s = u.x * u.x + u.y * u.y + u.z * u.z + u.w * u.w +
              v.x * v.x + v.y * v.y + v.z * v.z + v.w * v.w;
#pragma unroll
    for (int o = 32; o > 0; o >>= 1) s += __shfl_xor(s, o);
    float scale = 1.0f / fmaxf(sqrtf(s), 1e-12f);
    u.x *= scale; u.y *= scale; u.z *= scale; u.w *= scale;
    v.x *= scale; v.y *= scale; v.z *= scale; v.w *= scale;
    p[0] = u; p[1] = v;
}

// ---------------- launch ----------------

extern "C" void kernel_launch(void* const* d_in, const int* in_sizes, int n_in,
                              void* d_out, int out_size, void* d_ws, size_t ws_size,
                              hipStream_t stream) {
    const float* x      = (const float*)d_in[0];
    const int*   src    = (const int*)d_in[1];
    const int*   dst    = (const int*)d_in[2];
    const float* Wself  = (const float*)d_in[3];
    const float* Wneigh = (const float*)d_in[4];
    const float* bias   = (const float*)d_in[5];
    float* H = (float*)d_out;

    char* ws = (char*)d_ws;
    int* deg     = (int*)ws;                 // 10000
    int* offsets = deg + N_NODES;            // 10001
    int* cursor  = offsets + N_NODES + 1;    // 10000
    int* csr_src = cursor + N_NODES;         // 160000
    size_t int_bytes = ((size_t)(N_NODES * 3 + 1 + N_EDGES) * 4 + 255) & ~(size_t)255;
    __hip_bfloat16* Abuf = (__hip_bfloat16*)(ws + int_bytes);        // [10000][1024] bf16
    __hip_bfloat16* Wt   = Abuf + (size_t)N_NODES * K_TOT;           // [512][1024] bf16
    unsigned char*  x8   = (unsigned char*)(Wt + (size_t)D_OUT * K_TOT); // [10000][512] fp8

    hipMemsetAsync(deg, 0, N_NODES * sizeof(int), stream);

    k1_count_convw<<<625 + 512, 256, 0, stream>>>(dst, deg, Wself, Wneigh, Wt);
    k2_scan_convx<<<626, 1024, 0, stream>>>(deg, offsets, cursor, x, Abuf, x8);
    scatter_kernel<<<625, 256, 0, stream>>>(src, dst, cursor, csr_src);
    aggregate_kernel<<<2500, 256, 0, stream>>>(offsets, csr_src, x8, Abuf);

    gemm_kernel<<<632, 128, 0, stream>>>((const short*)Abuf, (const short*)Wt, bias, H);

    normalize_kernel<<<2500, 256, 0, stream>>>(H);
}